// Round 3
// baseline (156.027 us; speedup 1.0000x reference)
//
#include <hip/hip_runtime.h>

#define NROWS 8192
#define HALF_N 4096
#define DIM 512
#define INV_T 10.0f
#define NRB 64              // number of 128-row blocks
#define NBLOCKS 2080        // 64*65/2 upper-triangle block pairs
#define BK 64               // k elements per staging round
#define ROWB 128            // bytes per LDS tile row (BK*2)
#define ROUNDS 8            // 512 / BK

typedef __attribute__((ext_vector_type(8))) short short8;
typedef __attribute__((ext_vector_type(4))) float f32x4;

__device__ __forceinline__ ushort f32_to_bf16_rne(float x) {
  unsigned u = __float_as_uint(x);
  unsigned r = (u + 0x7fffu + ((u >> 16) & 1u)) >> 16;
  return (ushort)r;
}

__device__ __forceinline__ void async16(const void* g, void* l) {
  __builtin_amdgcn_global_load_lds(
      (const __attribute__((address_space(1))) unsigned int*)g,
      (__attribute__((address_space(3))) unsigned int*)l, 16, 0, 0);
}

// Kernel 1: L2-normalize rows of [f1;f2] -> bf16 Fn; zero rowsum + counter.
__global__ __launch_bounds__(256) void norm_cast_k(
    const float* __restrict__ f1, const float* __restrict__ f2,
    ushort* __restrict__ Fn, float* __restrict__ rowsum,
    unsigned* __restrict__ cnt) {
  int wave = threadIdx.x >> 6;
  int lane = threadIdx.x & 63;
  int row = blockIdx.x * 4 + wave;
  const float* src = (row < HALF_N) ? (f1 + (size_t)row * DIM)
                                    : (f2 + (size_t)(row - HALF_N) * DIM);
  const float4* p = reinterpret_cast<const float4*>(src + lane * 8);
  float4 v0 = p[0];
  float4 v1 = p[1];
  float ss = v0.x*v0.x + v0.y*v0.y + v0.z*v0.z + v0.w*v0.w
           + v1.x*v1.x + v1.y*v1.y + v1.z*v1.z + v1.w*v1.w;
  #pragma unroll
  for (int off = 1; off < 64; off <<= 1) ss += __shfl_xor(ss, off);
  float scale = 1.0f / fmaxf(sqrtf(ss), 1e-12f);
  union { ushort u[8]; short8 v; } o;
  o.u[0] = f32_to_bf16_rne(v0.x * scale);
  o.u[1] = f32_to_bf16_rne(v0.y * scale);
  o.u[2] = f32_to_bf16_rne(v0.z * scale);
  o.u[3] = f32_to_bf16_rne(v0.w * scale);
  o.u[4] = f32_to_bf16_rne(v1.x * scale);
  o.u[5] = f32_to_bf16_rne(v1.y * scale);
  o.u[6] = f32_to_bf16_rne(v1.z * scale);
  o.u[7] = f32_to_bf16_rne(v1.w * scale);
  *reinterpret_cast<short8*>(Fn + (size_t)row * DIM + lane * 8) = o.v;
  if (lane == 0) rowsum[row] = 0.0f;
  if (blockIdx.x == 0 && threadIdx.x == 0) *cnt = 0u;
}

// Kernel 2: symmetric upper-triangle sim GEMM + fused exp accumulation +
// last-block loss finalize. 128x128 tiles, BK=64 staging rounds via
// global_load_lds, 4 waves x (64x64) register tiles.
__global__ __launch_bounds__(256, 3) void sym_gemm_k(
    const ushort* __restrict__ Fn, float* __restrict__ rowsum,
    float* __restrict__ pairsim, unsigned* __restrict__ cnt,
    float* __restrict__ out) {
  // XCD-contiguous remap of the triangle index
  int bx = blockIdx.x;
  int gbx = (bx & 7) * (NBLOCKS / 8) + (bx >> 3);
  int rb = 0, rem = gbx;
  while (rem >= NRB - rb) { rem -= NRB - rb; ++rb; }
  const int cb = rb + rem;
  const int row0 = rb * 128, col0 = cb * 128;

  const int tid = threadIdx.x;
  const int wave = tid >> 6;
  const int lane = tid & 63;
  const int quad = lane >> 4;
  const int colid = lane & 15;
  const int wr0 = (wave >> 1) * 64;
  const int wc0 = (wave & 1) * 64;

  __shared__ ushort Alds[128 * BK];   // 16 KB, row stride 128 B (8 chunks)
  __shared__ ushort Blds[128 * BK];   // physical chunk = logical ^ (row&7)
  __shared__ float redrow[128];
  __shared__ float redcol[128];
  __shared__ float fred[4];
  __shared__ unsigned lastflag;

  if (tid < 128) { redrow[tid] = 0.0f; redcol[tid] = 0.0f; }

  // ---- staging addresses ----
  // Wave w stages A rows [w*32 + j*8, +8) (j=0..3) and same B rows.
  // Per inst: lane -> row r = base + (lane>>3), phys chunk lane&7;
  // global logical chunk = (lane&7) ^ (lane>>3)  (r&7 == lane>>3).
  const char* FnB = (const char*)Fn;
  const int lrow = lane >> 3;
  const int clog = (lane & 7) ^ lrow;
  const size_t laneoff = (size_t)lrow * (DIM * 2) + (size_t)clog * 16;
  const char* srcA = FnB + (size_t)(row0 + wave * 32) * (DIM * 2) + laneoff;
  const char* srcB = FnB + (size_t)(col0 + wave * 32) * (DIM * 2) + laneoff;
  ushort* dstA = Alds + wave * 32 * BK;
  ushort* dstB = Blds + wave * 32 * BK;

  // ---- fragment LDS pointers (constant across rounds) ----
  // A operand (16x16x32): lane holds A[m = colid][k = quad*8 + j]; sub-step s
  // selects k-half: logical chunk = s*4 + quad, phys = ^ (r&7).
  const ushort* afp[4][2];
  const ushort* bfp[4][2];
  #pragma unroll
  for (int t = 0; t < 4; ++t) {
    int ra = wr0 + t * 16 + colid;
    int rc = wc0 + t * 16 + colid;
    #pragma unroll
    for (int s = 0; s < 2; ++s) {
      afp[t][s] = Alds + ra * BK + (((s * 4 + quad) ^ (ra & 7)) << 3);
      bfp[t][s] = Blds + rc * BK + (((s * 4 + quad) ^ (rc & 7)) << 3);
    }
  }

  f32x4 acc[4][4];
  #pragma unroll
  for (int t = 0; t < 4; ++t)
    #pragma unroll
    for (int u = 0; u < 4; ++u) acc[t][u] = (f32x4){0.f, 0.f, 0.f, 0.f};

  for (int kc = 0; kc < ROUNDS; ++kc) {
    __syncthreads();                       // prior round's reads done
    const size_t ko = (size_t)kc * ROWB;
    #pragma unroll
    for (int j = 0; j < 4; ++j) {
      async16(srcA + (size_t)j * 8192 + ko, dstA + j * 512);
      async16(srcB + (size_t)j * 8192 + ko, dstB + j * 512);
    }
    __syncthreads();                       // drains DMA -> tiles visible

    #pragma unroll
    for (int s = 0; s < 2; ++s) {
      short8 af[4], bf[4];
      #pragma unroll
      for (int t = 0; t < 4; ++t) af[t] = *reinterpret_cast<const short8*>(afp[t][s]);
      #pragma unroll
      for (int u = 0; u < 4; ++u) bf[u] = *reinterpret_cast<const short8*>(bfp[u][s]);
      #pragma unroll
      for (int t = 0; t < 4; ++t)
        #pragma unroll
        for (int u = 0; u < 4; ++u)
          acc[t][u] = __builtin_amdgcn_mfma_f32_16x16x32_bf16(af[t], bf[u], acc[t][u], 0, 0, 0);
    }
  }

  // ---- epilogue: exp + row/col accumulation ----
  // C/D layout: col = lane&15, row = quad*4 + reg (m89-verified).
  float re[4][4];
  float ce[4];
  #pragma unroll
  for (int t = 0; t < 4; ++t)
    #pragma unroll
    for (int r = 0; r < 4; ++r) re[t][r] = 0.0f;
  #pragma unroll
  for (int u = 0; u < 4; ++u) ce[u] = 0.0f;

  #pragma unroll
  for (int t = 0; t < 4; ++t) {
    #pragma unroll
    for (int u = 0; u < 4; ++u) {
      f32x4 a = acc[t][u];
      const int gc = col0 + wc0 + u * 16 + colid;
      #pragma unroll
      for (int r = 0; r < 4; ++r) {
        int grow = row0 + wr0 + t * 16 + quad * 4 + r;
        float sim = a[r] * INV_T;
        float e = (gc > grow) ? __expf(sim) : 0.0f;  // strict upper triangle
        re[t][r] += e;
        ce[u] += e;
        if (gc == grow + HALF_N && grow < HALF_N) {
          atomicExch(&pairsim[grow], sim);   // device-coherent store
          atomicExch(&pairsim[gc], sim);
        }
      }
    }
  }

  #pragma unroll
  for (int t = 0; t < 4; ++t)
    #pragma unroll
    for (int r = 0; r < 4; ++r) {
      float v = re[t][r];
      v += __shfl_xor(v, 1); v += __shfl_xor(v, 2);
      v += __shfl_xor(v, 4); v += __shfl_xor(v, 8);
      if (colid == 0) atomicAdd(&redrow[wr0 + t * 16 + quad * 4 + r], v);
    }
  #pragma unroll
  for (int u = 0; u < 4; ++u) {
    float v = ce[u];
    v += __shfl_xor(v, 16); v += __shfl_xor(v, 32);
    if (lane < 16) atomicAdd(&redcol[wc0 + u * 16 + colid], v);
  }
  __syncthreads();
  if (tid < 128) atomicAdd(&rowsum[row0 + tid], redrow[tid]);
  else           atomicAdd(&rowsum[col0 + tid - 128], redcol[tid - 128]);
  __syncthreads();                         // all waves' atomics drained

  // ---- last-block loss finalize ----
  if (tid == 0) {
    __threadfence();                       // release our writes device-wide
    lastflag = (atomicAdd(cnt, 1u) == NBLOCKS - 1) ? 1u : 0u;
  }
  __syncthreads();
  if (lastflag) {
    __threadfence();                       // acquire: invalidate stale caches
    float local = 0.0f;
    for (int i = tid; i < NROWS; i += 256)
      local += logf(rowsum[i]) - pairsim[i];
    #pragma unroll
    for (int off = 1; off < 64; off <<= 1) local += __shfl_xor(local, off);
    if (lane == 0) fred[wave] = local;
    __syncthreads();
    if (tid == 0)
      out[0] = (fred[0] + fred[1] + fred[2] + fred[3]) * (1.0f / (float)NROWS);
  }
}

extern "C" void kernel_launch(void* const* d_in, const int* in_sizes, int n_in,
                              void* d_out, int out_size, void* d_ws, size_t ws_size,
                              hipStream_t stream) {
  const float* f1 = (const float*)d_in[0];
  const float* f2 = (const float*)d_in[1];
  ushort* Fn = (ushort*)d_ws;                                   // 8 MB bf16
  float* rowsum = (float*)((char*)d_ws + (size_t)NROWS * DIM * 2);
  float* pairsim = rowsum + NROWS;
  unsigned* cnt = (unsigned*)(pairsim + NROWS);
  float* out = (float*)d_out;

  norm_cast_k<<<NROWS / 4, 256, 0, stream>>>(f1, f2, Fn, rowsum, cnt);
  sym_gemm_k<<<NBLOCKS, 256, 0, stream>>>(Fn, rowsum, pairsim, cnt, out);
}

// Round 4
// 143.110 us; speedup vs baseline: 1.0903x; 1.0903x over previous
//
#include <hip/hip_runtime.h>

#define NROWS 8192
#define HALF_N 4096
#define DIM 512
#define INV_T 10.0f
#define NRB 64              // number of 128-row blocks
#define NBLOCKS 2080        // 64*65/2 upper-triangle block pairs

typedef __attribute__((ext_vector_type(8))) short short8;
typedef __attribute__((ext_vector_type(4))) float f32x4;

__device__ __forceinline__ ushort f32_to_bf16_rne(float x) {
  unsigned u = __float_as_uint(x);
  unsigned r = (u + 0x7fffu + ((u >> 16) & 1u)) >> 16;
  return (ushort)r;
}

__device__ __forceinline__ void async16(const void* g, void* l) {
  __builtin_amdgcn_global_load_lds(
      (const __attribute__((address_space(1))) unsigned int*)g,
      (__attribute__((address_space(3))) unsigned int*)l, 16, 0, 0);
}

// Kernel 1: L2-normalize rows of [f1;f2] -> bf16 Fn; zero rowsum + counter.
__global__ __launch_bounds__(256) void norm_cast_k(
    const float* __restrict__ f1, const float* __restrict__ f2,
    ushort* __restrict__ Fn, float* __restrict__ rowsum,
    unsigned* __restrict__ cnt) {
  int wave = threadIdx.x >> 6;
  int lane = threadIdx.x & 63;
  int row = blockIdx.x * 4 + wave;
  const float* src = (row < HALF_N) ? (f1 + (size_t)row * DIM)
                                    : (f2 + (size_t)(row - HALF_N) * DIM);
  const float4* p = reinterpret_cast<const float4*>(src + lane * 8);
  float4 v0 = p[0];
  float4 v1 = p[1];
  float ss = v0.x*v0.x + v0.y*v0.y + v0.z*v0.z + v0.w*v0.w
           + v1.x*v1.x + v1.y*v1.y + v1.z*v1.z + v1.w*v1.w;
  #pragma unroll
  for (int off = 1; off < 64; off <<= 1) ss += __shfl_xor(ss, off);
  float scale = 1.0f / fmaxf(sqrtf(ss), 1e-12f);
  union { ushort u[8]; short8 v; } o;
  o.u[0] = f32_to_bf16_rne(v0.x * scale);
  o.u[1] = f32_to_bf16_rne(v0.y * scale);
  o.u[2] = f32_to_bf16_rne(v0.z * scale);
  o.u[3] = f32_to_bf16_rne(v0.w * scale);
  o.u[4] = f32_to_bf16_rne(v1.x * scale);
  o.u[5] = f32_to_bf16_rne(v1.y * scale);
  o.u[6] = f32_to_bf16_rne(v1.z * scale);
  o.u[7] = f32_to_bf16_rne(v1.w * scale);
  *reinterpret_cast<short8*>(Fn + (size_t)row * DIM + lane * 8) = o.v;
  if (lane == 0) rowsum[row] = 0.0f;
  if (blockIdx.x == 0 && threadIdx.x == 0) *cnt = 0u;
}

// Kernel 2: symmetric upper-triangle sim GEMM + fused exp accumulation +
// last-block loss finalize. 128x128 tiles, BK=32, DOUBLE-BUFFERED
// global_load_lds staging (loads for round kc+1 fly during compute of kc).
__global__ __launch_bounds__(256, 3) void sym_gemm_k(
    const ushort* __restrict__ Fn, float* __restrict__ rowsum,
    float* __restrict__ pairsim, unsigned* __restrict__ cnt,
    float* __restrict__ out) {
  // XCD-contiguous remap of the triangle index
  int bx = blockIdx.x;
  int gbx = (bx & 7) * (NBLOCKS / 8) + (bx >> 3);
  int rb = 0, rem = gbx;
  while (rem >= NRB - rb) { rem -= NRB - rb; ++rb; }
  const int cb = rb + rem;
  const int row0 = rb * 128, col0 = cb * 128;

  const int tid = threadIdx.x;
  const int wave = tid >> 6;
  const int lane = tid & 63;
  const int quad = lane >> 4;
  const int colid = lane & 15;
  const int wr0 = (wave >> 1) * 64;
  const int wc0 = (wave & 1) * 64;

  // Double-buffered tiles: 128 rows x 32 k bf16 = 64 B/row, 4 x 16B chunks.
  // Physical chunk = logical ^ ((row>>1)&3) -> conflict-free frag reads.
  __shared__ ushort Alds[2][128 * 32];   // 2 x 8 KB
  __shared__ ushort Blds[2][128 * 32];
  __shared__ float redrow[128];
  __shared__ float redcol[128];
  __shared__ float fred[4];
  __shared__ unsigned lastflag;

  if (tid < 128) { redrow[tid] = 0.0f; redcol[tid] = 0.0f; }

  // ---- staging addresses (R2 pattern) ----
  // 16 insts/round: wave w owns A insts {w, w+4}, B insts {w, w+4};
  // inst i covers rows [i*16, i*16+16): lane -> r = i*16 + (lane>>2),
  // phys chunk = lane&3, logical chunk = (lane&3) ^ ((lane>>3)&3).
  const char* FnB = (const char*)Fn;
  const char* srcA[2]; const char* srcB[2];
  ushort* dstA[2]; ushort* dstB[2];
  #pragma unroll
  for (int seg = 0; seg < 2; ++seg) {
    int inst = wave + seg * 4;
    int r = inst * 16 + (lane >> 2);
    int c = (lane & 3) ^ ((r >> 1) & 3);
    srcA[seg] = FnB + (size_t)(row0 + r) * (DIM * 2) + c * 16;
    srcB[seg] = FnB + (size_t)(col0 + r) * (DIM * 2) + c * 16;
    dstA[seg] = &Alds[0][inst * 512];   // 1 KB per inst
    dstB[seg] = &Blds[0][inst * 512];
  }

  auto issue = [&](int kc, int buf) {
    const size_t ko = (size_t)kc * 64;  // 32 k-elems = 64 B per row
    const int bo = buf * 4096;          // ushorts per buffer
    #pragma unroll
    for (int seg = 0; seg < 2; ++seg) {
      async16(srcA[seg] + ko, dstA[seg] + bo);
      async16(srcB[seg] + ko, dstB[seg] + bo);
    }
  };

  // ---- fragment LDS pointers (buffer 0; +4096 for buffer 1) ----
  const ushort* afp[4]; const ushort* bfp[4];
  #pragma unroll
  for (int t = 0; t < 4; ++t) {
    int ra = wr0 + t * 16 + colid;
    afp[t] = &Alds[0][ra * 32 + ((quad ^ ((ra >> 1) & 3)) << 3)];
    int rc = wc0 + t * 16 + colid;
    bfp[t] = &Blds[0][rc * 32 + ((quad ^ ((rc >> 1) & 3)) << 3)];
  }

  f32x4 acc[4][4];
  #pragma unroll
  for (int t = 0; t < 4; ++t)
    #pragma unroll
    for (int u = 0; u < 4; ++u) acc[t][u] = (f32x4){0.f, 0.f, 0.f, 0.f};

  auto compute = [&](int buf) {
    const int bo = buf * 4096;
    short8 af[4], bfr[4];
    #pragma unroll
    for (int t = 0; t < 4; ++t) af[t] = *reinterpret_cast<const short8*>(afp[t] + bo);
    #pragma unroll
    for (int u = 0; u < 4; ++u) bfr[u] = *reinterpret_cast<const short8*>(bfp[u] + bo);
    #pragma unroll
    for (int t = 0; t < 4; ++t)
      #pragma unroll
      for (int u = 0; u < 4; ++u)
        acc[t][u] = __builtin_amdgcn_mfma_f32_16x16x32_bf16(af[t], bfr[u], acc[t][u], 0, 0, 0);
  };

  issue(0, 0);                           // prologue: round 0 into buf 0
  for (int kc = 0; kc < 16; kc += 2) {
    __syncthreads();                     // publishes buf0(kc); buf1 free
    issue(kc + 1, 1);                    // kc+1 <= 15 always
    compute(0);
    __syncthreads();                     // publishes buf1(kc+1); buf0 free
    if (kc + 2 < 16) issue(kc + 2, 0);
    compute(1);
  }

  // ---- epilogue: exp + row/col accumulation ----
  // C/D layout: col = lane&15, row = quad*4 + reg (m89-verified).
  float re[4][4];
  float ce[4];
  #pragma unroll
  for (int t = 0; t < 4; ++t)
    #pragma unroll
    for (int r = 0; r < 4; ++r) re[t][r] = 0.0f;
  #pragma unroll
  for (int u = 0; u < 4; ++u) ce[u] = 0.0f;

  #pragma unroll
  for (int t = 0; t < 4; ++t) {
    #pragma unroll
    for (int u = 0; u < 4; ++u) {
      f32x4 a = acc[t][u];
      const int gc = col0 + wc0 + u * 16 + colid;
      #pragma unroll
      for (int r = 0; r < 4; ++r) {
        int grow = row0 + wr0 + t * 16 + quad * 4 + r;
        float sim = a[r] * INV_T;
        float e = (gc > grow) ? __expf(sim) : 0.0f;  // strict upper triangle
        re[t][r] += e;
        ce[u] += e;
        if (gc == grow + HALF_N && grow < HALF_N) {
          atomicExch(&pairsim[grow], sim);   // device-coherent store
          atomicExch(&pairsim[gc], sim);
        }
      }
    }
  }

  #pragma unroll
  for (int t = 0; t < 4; ++t)
    #pragma unroll
    for (int r = 0; r < 4; ++r) {
      float v = re[t][r];
      v += __shfl_xor(v, 1); v += __shfl_xor(v, 2);
      v += __shfl_xor(v, 4); v += __shfl_xor(v, 8);
      if (colid == 0) atomicAdd(&redrow[wr0 + t * 16 + quad * 4 + r], v);
    }
  #pragma unroll
  for (int u = 0; u < 4; ++u) {
    float v = ce[u];
    v += __shfl_xor(v, 16); v += __shfl_xor(v, 32);
    if (lane < 16) atomicAdd(&redcol[wc0 + u * 16 + colid], v);
  }
  __syncthreads();
  if (tid < 128) atomicAdd(&rowsum[row0 + tid], redrow[tid]);
  else           atomicAdd(&rowsum[col0 + tid - 128], redcol[tid - 128]);
  __syncthreads();   // drains vmcnt: our device-scope atomics are at the
                     // coherence point before cnt is bumped (no L2 flush!)

  // ---- last-block loss finalize ----
  if (tid == 0)
    lastflag = (atomicAdd(cnt, 1u) == NBLOCKS - 1) ? 1u : 0u;
  __syncthreads();
  if (lastflag) {
    __threadfence();   // acquire side only (runs in ONE block)
    float local = 0.0f;
    for (int i = tid; i < NROWS; i += 256) {
      float rs = __hip_atomic_load(&rowsum[i], __ATOMIC_RELAXED,
                                   __HIP_MEMORY_SCOPE_AGENT);
      float ps = __hip_atomic_load(&pairsim[i], __ATOMIC_RELAXED,
                                   __HIP_MEMORY_SCOPE_AGENT);
      local += __logf(rs) - ps;
    }
    #pragma unroll
    for (int off = 1; off < 64; off <<= 1) local += __shfl_xor(local, off);
    if (lane == 0) fred[wave] = local;
    __syncthreads();
    if (tid == 0)
      out[0] = (fred[0] + fred[1] + fred[2] + fred[3]) * (1.0f / (float)NROWS);
  }
}

extern "C" void kernel_launch(void* const* d_in, const int* in_sizes, int n_in,
                              void* d_out, int out_size, void* d_ws, size_t ws_size,
                              hipStream_t stream) {
  const float* f1 = (const float*)d_in[0];
  const float* f2 = (const float*)d_in[1];
  ushort* Fn = (ushort*)d_ws;                                   // 8 MB bf16
  float* rowsum = (float*)((char*)d_ws + (size_t)NROWS * DIM * 2);
  float* pairsim = rowsum + NROWS;
  unsigned* cnt = (unsigned*)(pairsim + NROWS);
  float* out = (float*)d_out;

  norm_cast_k<<<NROWS / 4, 256, 0, stream>>>(f1, f2, Fn, rowsum, cnt);
  sym_gemm_k<<<NBLOCKS, 256, 0, stream>>>(Fn, rowsum, pairsim, cnt, out);
}